// Round 6
// baseline (496.272 us; speedup 1.0000x reference)
//
#include <hip/hip_runtime.h>
#include <hip/hip_bf16.h>
#include <stdint.h>

#define B_ 4
#define S_ 2048
#define E_ 2048
#define H_ 16
#define D_ 128
#define M_ (B_ * S_)  // 8192 rows

typedef unsigned short ushort_t;
typedef unsigned int uint_t;
typedef __attribute__((ext_vector_type(4))) float f32x4;
typedef __attribute__((ext_vector_type(2))) uint_t u32x2;
typedef __attribute__((ext_vector_type(8))) short bf16x8;

__device__ __forceinline__ ushort_t f2bf(float f) {
  uint_t u = __float_as_uint(f);
  u += 0x7FFFu + ((u >> 16) & 1u);  // RNE
  return (ushort_t)(u >> 16);
}
__device__ __forceinline__ float bf2f(ushort_t h) {
  return __uint_as_float(((uint_t)h) << 16);
}
__device__ __forceinline__ uint_t cvt_pk_bf16(float lo, float hi) {
  uint_t r;
  asm("v_cvt_pk_bf16_f32 %0, %1, %2" : "=v"(r) : "v"(lo), "v"(hi));
  return r;
}

#define GLOAD_LDS16(gp, lp)                                   \
  __builtin_amdgcn_global_load_lds(                           \
      (__attribute__((address_space(1))) void*)(gp),          \
      (__attribute__((address_space(3))) void*)(lp), 16, 0, 0)

// ---------------------------------------------------------------- converts
__global__ void f32_to_bf16(const float* __restrict__ in, ushort_t* __restrict__ out,
                            size_t n4) {
  const size_t stride = (size_t)gridDim.x * blockDim.x;
  for (size_t i = (size_t)blockIdx.x * blockDim.x + threadIdx.x; i < n4; i += stride) {
    const f32x4 f = __builtin_nontemporal_load((const f32x4*)in + i);
    u32x2 o;
    o[0] = (uint_t)f2bf(f[0]) | ((uint_t)f2bf(f[1]) << 16);
    o[1] = (uint_t)f2bf(f[2]) | ((uint_t)f2bf(f[3]) << 16);
    __builtin_nontemporal_store(o, (u32x2*)out + i);
  }
}

// ---------------------------------------------------------------- GEMM 256x256, BK=64, 8 waves
// C[M][N] = A[M][K]·Bw[N][K]^T + bias. 4-phase/K-tile schedule (m201 mechanism set):
// per phase {ds_read subtile || stage 1 slab via global_load_lds -> barrier ->
// lgkmcnt(0) -> 16 MFMA (setprio)}. Slabs are (matrix, k-half) 16KB units so the
// waits stay counted: vmcnt(4) at phases 0 and 2, never 0 until the tail tile.
// Epilogue repacks acc through LDS -> fully coalesced row-contiguous stores
// (MODE 1 f32 nt, MODE 2 bf16+RoPE, MODE 3 bf16 V-transpose to [B][H][D][S]).
template <int MODE>
__global__ __launch_bounds__(512, 1) void gemm256(const ushort_t* __restrict__ A,
                                                  const ushort_t* __restrict__ Bw,
                                                  const float* __restrict__ bias,
                                                  void* __restrict__ Cv) {
  // main loop: 2 bufs x 64KB (A 32KB: [kk][proven row-pair layout], B same) = 128KB
  // epilogue: float Cl[128][260] (row-major) or Ct[256][132] (transposed)
  __shared__ __align__(16) char lds[135168];
  const int tid = threadIdx.x;
  const int w = tid >> 6, l = tid & 63, g = l >> 4, ln = l & 15;
  const int wm = w >> 2, wn = w & 3;

  const int flat = blockIdx.x;  // 256 blocks; XCD-chunked bijective swizzle
  const int swz = (flat & 7) * 32 + (flat >> 3);
  const int m0 = (swz >> 3) * 256, n0 = (swz & 7) * 256;

  const ushort_t* Ab = A + (size_t)m0 * E_;
  const ushort_t* Bb = Bw + (size_t)n0 * E_;

  // staging source (per-lane, inverse chunk-XOR swizzle); dest is linear
  int srcRow[2], srcCc[2];
#pragma unroll
  for (int i = 0; i < 2; i++) {
    const int c = i * 512 + tid;       // chunk 0..1023 of one 16KB slab
    const int r2 = c >> 3;             // row-pair 0..127
    const int j = (c & 7) ^ (r2 & 7);
    srcRow[i] = 2 * r2 + (j >> 2);
    srcCc[i] = (j & 3) * 8;
  }

  const int NT = E_ / 64;  // 32 K-tiles

  auto STAGE = [&](int t_, int mat, int kk) {
    char* dst = lds + (t_ & 1) * 65536 + mat * 32768 + kk * 16384;
    const ushort_t* src = mat ? Bb : Ab;
#pragma unroll
    for (int i = 0; i < 2; i++)
      GLOAD_LDS16(src + (size_t)srcRow[i] * E_ + t_ * 64 + kk * 32 + srcCc[i],
                  dst + (i * 512 + w * 64) * 16);
  };

  // read-side addressing (proven conflict-free row-pair chunk-XOR layout)
  const int rp = ln >> 1;
  const int chunkl = ((((ln & 1) << 2) | g) ^ rp);
  const int aBase = wm * 8192 + rp * 128 + chunkl * 16;           // + kk*16384 + mh*4096 + ai*1024
  const int bBase = 32768 + wn * 4096 + rp * 128 + chunkl * 16;   // + kk*16384 + ni*1024

  f32x4 acc[8][4];
#pragma unroll
  for (int mi = 0; mi < 8; mi++)
#pragma unroll
    for (int ni = 0; ni < 4; ni++)
#pragma unroll
      for (int r = 0; r < 4; r++) acc[mi][ni][r] = 0.f;

  STAGE(0, 0, 0);
  STAGE(0, 1, 0);
  STAGE(0, 0, 1);
  STAGE(0, 1, 1);

  for (int t = 0; t < NT; t++) {
    const char* bp = lds + (t & 1) * 65536;
    const bool nxt = (t + 1 < NT);
    bf16x8 bfr[4], af[4];

    // ---- phase 0 (kk=0, mh=0)
    asm volatile("s_waitcnt vmcnt(4)" ::: "memory");  // slabs A.k0,B.k0 of tile t landed
    __builtin_amdgcn_s_barrier();
#pragma unroll
    for (int ni = 0; ni < 4; ni++) bfr[ni] = *(const bf16x8*)(bp + bBase + ni * 1024);
#pragma unroll
    for (int ai = 0; ai < 4; ai++) af[ai] = *(const bf16x8*)(bp + aBase + ai * 1024);
    if (nxt) STAGE(t + 1, 0, 0);
    asm volatile("s_waitcnt lgkmcnt(0)" ::: "memory");
    __builtin_amdgcn_sched_barrier(0);
    __builtin_amdgcn_s_setprio(1);
#pragma unroll
    for (int ai = 0; ai < 4; ai++)
#pragma unroll
      for (int ni = 0; ni < 4; ni++)
        acc[ai][ni] = __builtin_amdgcn_mfma_f32_16x16x32_bf16(af[ai], bfr[ni], acc[ai][ni], 0, 0, 0);
    __builtin_amdgcn_s_setprio(0);

    // ---- phase 1 (kk=0, mh=1)
    __builtin_amdgcn_s_barrier();
#pragma unroll
    for (int ai = 0; ai < 4; ai++) af[ai] = *(const bf16x8*)(bp + aBase + 4096 + ai * 1024);
    if (nxt) STAGE(t + 1, 1, 0);
    asm volatile("s_waitcnt lgkmcnt(0)" ::: "memory");
    __builtin_amdgcn_sched_barrier(0);
    __builtin_amdgcn_s_setprio(1);
#pragma unroll
    for (int ai = 0; ai < 4; ai++)
#pragma unroll
      for (int ni = 0; ni < 4; ni++)
        acc[4 + ai][ni] =
            __builtin_amdgcn_mfma_f32_16x16x32_bf16(af[ai], bfr[ni], acc[4 + ai][ni], 0, 0, 0);
    __builtin_amdgcn_s_setprio(0);

    // ---- phase 2 (kk=1, mh=0)
    if (nxt)
      asm volatile("s_waitcnt vmcnt(4)" ::: "memory");  // slabs A.k1,B.k1 of tile t landed
    else
      asm volatile("s_waitcnt vmcnt(0)" ::: "memory");
    __builtin_amdgcn_s_barrier();
#pragma unroll
    for (int ni = 0; ni < 4; ni++) bfr[ni] = *(const bf16x8*)(bp + bBase + 16384 + ni * 1024);
#pragma unroll
    for (int ai = 0; ai < 4; ai++) af[ai] = *(const bf16x8*)(bp + aBase + 16384 + ai * 1024);
    if (nxt) STAGE(t + 1, 0, 1);
    asm volatile("s_waitcnt lgkmcnt(0)" ::: "memory");
    __builtin_amdgcn_sched_barrier(0);
    __builtin_amdgcn_s_setprio(1);
#pragma unroll
    for (int ai = 0; ai < 4; ai++)
#pragma unroll
      for (int ni = 0; ni < 4; ni++)
        acc[ai][ni] = __builtin_amdgcn_mfma_f32_16x16x32_bf16(af[ai], bfr[ni], acc[ai][ni], 0, 0, 0);
    __builtin_amdgcn_s_setprio(0);

    // ---- phase 3 (kk=1, mh=1)
    __builtin_amdgcn_s_barrier();
#pragma unroll
    for (int ai = 0; ai < 4; ai++)
      af[ai] = *(const bf16x8*)(bp + aBase + 16384 + 4096 + ai * 1024);
    if (nxt) STAGE(t + 1, 1, 1);
    asm volatile("s_waitcnt lgkmcnt(0)" ::: "memory");
    __builtin_amdgcn_sched_barrier(0);
    __builtin_amdgcn_s_setprio(1);
#pragma unroll
    for (int ai = 0; ai < 4; ai++)
#pragma unroll
      for (int ni = 0; ni < 4; ni++)
        acc[4 + ai][ni] =
            __builtin_amdgcn_mfma_f32_16x16x32_bf16(af[ai], bfr[ni], acc[4 + ai][ni], 0, 0, 0);
    __builtin_amdgcn_s_setprio(0);
  }

  // ---------------- epilogue: LDS repack -> coalesced stores
  float bv[4];
#pragma unroll
  for (int ni = 0; ni < 4; ni++) bv[ni] = bias[n0 + wn * 64 + ni * 16 + ln];

#pragma unroll
  for (int mh = 0; mh < 2; mh++) {
    __builtin_amdgcn_s_barrier();
    if (MODE == 3) {
      // transposed repack: Ct[256 cols][132] f32; per-lane b128 writes (row-contig)
      float* Ct = (float*)lds;
#pragma unroll
      for (int ai = 0; ai < 4; ai++)
#pragma unroll
        for (int ni = 0; ni < 4; ni++) {
          const int col = wn * 64 + ni * 16 + ln;
          const int rr = wm * 64 + ai * 16 + g * 4;
          f32x4 v = acc[mh * 4 + ai][ni];
#pragma unroll
          for (int r = 0; r < 4; r++) v[r] += bv[ni];
          *(f32x4*)(Ct + col * 132 + rr) = v;
        }
      __builtin_amdgcn_s_barrier();
#pragma unroll
      for (int i = 0; i < 16; i++) {
        const int c = i * 512 + tid;
        const int rq = c & 31, cl = c >> 5;
        const f32x4 v = *(const f32x4*)((const float*)lds + cl * 132 + rq * 4);
        const int gcol = n0 + cl;
        const int hh = gcol >> 7, d = gcol & 127;
        const int bb = m0 >> 11;
        const int s = (m0 & (S_ - 1)) + (rq >> 4) * 128 + mh * 64 + (rq & 15) * 4;
        *(uint2*)((ushort_t*)Cv + (((size_t)(bb * H_ + hh) * D_ + d) * S_ + s)) =
            make_uint2(cvt_pk_bf16(v[0], v[1]), cvt_pk_bf16(v[2], v[3]));
      }
    } else {
      // row-major repack: Cl[128 rows][260] f32
      float* Cl = (float*)lds;
#pragma unroll
      for (int ai = 0; ai < 4; ai++)
#pragma unroll
        for (int ni = 0; ni < 4; ni++) {
          const int col = wn * 64 + ni * 16 + ln;
          const int rr0 = wm * 64 + ai * 16 + g * 4;
#pragma unroll
          for (int r = 0; r < 4; r++)
            Cl[(rr0 + r) * 260 + col] = acc[mh * 4 + ai][ni][r] + bv[ni];
        }
      __builtin_amdgcn_s_barrier();
#pragma unroll
      for (int i = 0; i < 16; i++) {
        const int c = i * 512 + tid;
        const int chk = c & 63, rr = c >> 6;
        const f32x4 v = *(const f32x4*)((const float*)lds + rr * 260 + chk * 4);
        const int grow = m0 + (rr >> 6) * 128 + mh * 64 + (rr & 63);
        const int gcol = n0 + chk * 4;
        if (MODE == 1) {  // f32 out, 16B coalesced nt
          __builtin_nontemporal_store(v, (f32x4*)((float*)Cv + (size_t)grow * E_ + gcol));
        } else {  // MODE 2: RoPE + bf16, 8B coalesced
          const int s = grow & (S_ - 1);
          const int ip0 = (gcol & 127) >> 1;
          float sn0, cs0, sn1, cs1;
          sincosf((float)s * exp2f(-0.20762050593046f * (float)ip0), &sn0, &cs0);
          sincosf((float)s * exp2f(-0.20762050593046f * (float)(ip0 + 1)), &sn1, &cs1);
          const float re0 = v[0] * cs0 - v[1] * sn0, ro0 = v[0] * sn0 + v[1] * cs0;
          const float re1 = v[2] * cs1 - v[3] * sn1, ro1 = v[2] * sn1 + v[3] * cs1;
          *(uint2*)((ushort_t*)Cv + (size_t)grow * E_ + gcol) =
              make_uint2(cvt_pk_bf16(re0, ro0), cvt_pk_bf16(re1, ro1));
        }
      }
    }
  }
}

// ---------------------------------------------------------------- flash attention (causal)
// (unchanged from round 5: balanced pairs, swapped QK^T, counted vmcnt, defer-max,
// XCD-grouped grid)
__global__ __launch_bounds__(256, 2) void attn_fwd(const ushort_t* __restrict__ Q,
                                                   const ushort_t* __restrict__ K,
                                                   const ushort_t* __restrict__ Vt,
                                                   ushort_t* __restrict__ O) {
  const int flat = blockIdx.x;
  const int pair = flat >> 6;   // 0..7
  const int bh = flat & 63;     // XCD = bh%8 for all 8 pairs of this bh
  const int b = bh >> 4, h = bh & 15;
  const int tid = threadIdx.x;
  const int w = tid >> 6, l = tid & 63, g = l >> 4, ln = l & 15;

  __shared__ ushort_t Ks[2][64 * 128];  // 32 KB
  __shared__ ushort_t Vs[2][128 * 64];  // 32 KB
  __shared__ ushort_t Ps[4][32 * 64];   // 16 KB, XOR-swizzled rows

  const ushort_t* Kb = K + (size_t)(b * S_) * E_ + h * D_;
  const ushort_t* Vb = Vt + (size_t)(b * H_ + h) * D_ * S_;
  const float scale = 0.08838834764831845f;  // D^-0.5

#define STAGE_KV(buf, kv0_)                                                      \
  do {                                                                           \
    _Pragma("unroll") for (int i = 0; i < 4; i++) {                              \
      const int c = i * 256 + tid;                                               \
      const int row = c >> 4, sl = c & 15;                                       \
      const int gs = sl ^ (row & 7);                                             \
      GLOAD_LDS16(Kb + (size_t)((kv0_) + row) * E_ + gs * 8,                     \
                  (char*)(&Ks[buf][0]) + (i * 256 + w * 64) * 16);               \
    }                                                                            \
    _Pragma("unroll") for (int i = 0; i < 4; i++) {                              \
      const int c = i * 256 + tid;                                               \
      const int row = c >> 3, sl = c & 7;                                        \
      const int gs = sl ^ (row & 7);                                             \
      GLOAD_LDS16(Vb + (size_t)row * S_ + (kv0_) + gs * 8,                       \
                  (char*)(&Vs[buf][0]) + (i * 256 + w * 64) * 16);               \
    }                                                                            \
  } while (0)

  for (int pass = 0; pass < 2; pass++) {
    const int u = (pass == 0) ? pair : (15 - pair);
    const int q0 = u * 128;
    const int wrow0 = q0 + w * 32;

    bf16x8 qf[2][4];
    {
      const ushort_t* qb = Q + (size_t)(b * S_ + wrow0) * E_ + h * D_;
#pragma unroll
      for (int mi = 0; mi < 2; mi++)
#pragma unroll
        for (int kk = 0; kk < 4; kk++) {
          bf16x8 v = *(const bf16x8*)(qb + (size_t)(mi * 16 + ln) * E_ + kk * 32 + g * 8);
#pragma unroll
          for (int j = 0; j < 8; j++) v[j] = (short)f2bf(bf2f((ushort_t)v[j]) * scale);
          qf[mi][kk] = v;
        }
    }

    f32x4 oacc[2][8];
#pragma unroll
    for (int mi = 0; mi < 2; mi++)
#pragma unroll
      for (int nd = 0; nd < 8; nd++)
#pragma unroll
        for (int r = 0; r < 4; r++) oacc[mi][nd][r] = 0.f;
    float mrun[2], srun[2];
#pragma unroll
    for (int mi = 0; mi < 2; mi++) {
      mrun[mi] = -__builtin_inff();
      srun[mi] = 0.f;
    }

    const int ntu = 2 * u + 2;
    STAGE_KV(0, 0);

    for (int t = 0; t < ntu; t++) {
      const int kv0 = t * 64;
      const int cur = t & 1;
      if (t + 1 < ntu) {
        STAGE_KV(cur ^ 1, kv0 + 64);
        asm volatile("s_waitcnt vmcnt(8)" ::: "memory");
      } else {
        asm volatile("s_waitcnt vmcnt(0)" ::: "memory");
      }
      __builtin_amdgcn_s_barrier();
      __builtin_amdgcn_sched_barrier(0);

      if (kv0 <= wrow0 + 31) {
        const ushort_t* Kst = &Ks[cur][0];
        const ushort_t* Vst = &Vs[cur][0];
        f32x4 sa[2][4];
#pragma unroll
        for (int mi = 0; mi < 2; mi++)
#pragma unroll
          for (int ni = 0; ni < 4; ni++)
#pragma unroll
            for (int r = 0; r < 4; r++) sa[mi][ni][r] = 0.f;
        __builtin_amdgcn_s_setprio(1);
#pragma unroll
        for (int kk = 0; kk < 4; kk++) {
          bf16x8 kf[4];
#pragma unroll
          for (int ni = 0; ni < 4; ni++) {
            const int row = ni * 16 + ln;
            const int sl = (kk * 4 + g) ^ (row & 7);
            kf[ni] = *(const bf16x8*)(Kst + row * 128 + sl * 8);
          }
#pragma unroll
          for (int mi = 0; mi < 2; mi++)
#pragma unroll
            for (int ni = 0; ni < 4; ni++)
              sa[mi][ni] =
                  __builtin_amdgcn_mfma_f32_16x16x32_bf16(kf[ni], qf[mi][kk], sa[mi][ni], 0, 0, 0);
        }
        __builtin_amdgcn_s_setprio(0);
        if (kv0 + 63 > wrow0) {
#pragma unroll
          for (int mi = 0; mi < 2; mi++) {
            const int lim = wrow0 + mi * 16 + ln - kv0;
#pragma unroll
            for (int ni = 0; ni < 4; ni++)
#pragma unroll
              for (int r = 0; r < 4; r++)
                if (ni * 16 + g * 4 + r > lim) sa[mi][ni][r] = -__builtin_inff();
          }
        }
#pragma unroll
        for (int mi = 0; mi < 2; mi++) {
          float vmax = -__builtin_inff();
#pragma unroll
          for (int ni = 0; ni < 4; ni++)
#pragma unroll
            for (int r = 0; r < 4; r++) vmax = fmaxf(vmax, sa[mi][ni][r]);
          vmax = fmaxf(vmax, __shfl_xor(vmax, 16));
          vmax = fmaxf(vmax, __shfl_xor(vmax, 32));
          if (!__all(vmax - mrun[mi] <= 8.0f)) {  // T13 defer-max
            const float mnew = fmaxf(mrun[mi], vmax);
            const float fs = __expf(mrun[mi] - mnew);
            mrun[mi] = mnew;
            srun[mi] *= fs;
#pragma unroll
            for (int nd = 0; nd < 8; nd++)
#pragma unroll
              for (int r = 0; r < 4; r++) oacc[mi][nd][r] *= fs;
          }
          const float m = mrun[mi];
          float psum = 0.f;
#pragma unroll
          for (int ni = 0; ni < 4; ni++) {
            float p0 = __expf(sa[mi][ni][0] - m);
            float p1 = __expf(sa[mi][ni][1] - m);
            float p2 = __expf(sa[mi][ni][2] - m);
            float p3 = __expf(sa[mi][ni][3] - m);
            psum += (p0 + p1) + (p2 + p3);
            const int byteW =
                (((mi * 16 + ln) * 64 + ni * 16 + g * 4) * 2) ^ ((ln & 7) << 4);
            *(uint2*)((char*)(&Ps[w][0]) + byteW) =
                make_uint2(cvt_pk_bf16(p0, p1), cvt_pk_bf16(p2, p3));
          }
          psum += __shfl_xor(psum, 16);
          psum += __shfl_xor(psum, 32);
          srun[mi] += psum;
        }
        asm volatile("s_waitcnt lgkmcnt(0)" ::: "memory");
        __builtin_amdgcn_sched_barrier(0);
        __builtin_amdgcn_s_setprio(1);
#pragma unroll
        for (int ks = 0; ks < 2; ks++) {
          bf16x8 pf[2];
#pragma unroll
          for (int mi = 0; mi < 2; mi++) {
            const int byteR =
                (((mi * 16 + ln) * 64 + ks * 32 + g * 8) * 2) ^ ((ln & 7) << 4);
            pf[mi] = *(const bf16x8*)((const char*)(&Ps[w][0]) + byteR);
          }
#pragma unroll
          for (int nd = 0; nd < 8; nd++) {
            const int row = nd * 16 + ln;
            const int sl = (ks * 4 + g) ^ (row & 7);
            const bf16x8 vf = *(const bf16x8*)(Vst + row * 64 + sl * 8);
#pragma unroll
            for (int mi = 0; mi < 2; mi++)
              oacc[mi][nd] =
                  __builtin_amdgcn_mfma_f32_16x16x32_bf16(vf, pf[mi], oacc[mi][nd], 0, 0, 0);
          }
        }
        __builtin_amdgcn_s_setprio(0);
      }
      __builtin_amdgcn_s_barrier();
    }

    // ---- epilogue
    {
      ushort_t* Ob = O + (size_t)(b * S_ + q0 + w * 32) * E_ + h * D_;
#pragma unroll
      for (int mi = 0; mi < 2; mi++) {
        const float inv = 1.0f / srun[mi];
#pragma unroll
        for (int nd = 0; nd < 8; nd++) {
          const uint_t lo = cvt_pk_bf16(oacc[mi][nd][0] * inv, oacc[mi][nd][1] * inv);
          const uint_t hi = cvt_pk_bf16(oacc[mi][nd][2] * inv, oacc[mi][nd][3] * inv);
          *(uint2*)(Ob + (size_t)(mi * 16 + ln) * E_ + nd * 16 + g * 4) = make_uint2(lo, hi);
        }
      }
    }
  }
#undef STAGE_KV
}

// ---------------------------------------------------------------- launch
extern "C" void kernel_launch(void* const* d_in, const int* in_sizes, int n_in,
                              void* d_out, int out_size, void* d_ws, size_t ws_size,
                              hipStream_t stream) {
  const float* x = (const float*)d_in[0];
  const float* Wq = (const float*)d_in[1];
  const float* bq = (const float*)d_in[2];
  const float* Wk = (const float*)d_in[3];
  const float* bk = (const float*)d_in[4];
  const float* Wv = (const float*)d_in[5];
  const float* bv = (const float*)d_in[6];
  const float* Wo = (const float*)d_in[7];
  const float* bo = (const float*)d_in[8];
  float* out = (float*)d_out;

  ushort_t* ws = (ushort_t*)d_ws;
  const size_t SZ = (size_t)M_ * E_;   // 16,777,216
  const size_t WSZ = (size_t)E_ * E_;  // 4,194,304
  ushort_t* xb = ws;            // x bf16; reused as attention output after projections
  ushort_t* Qb = ws + SZ;
  ushort_t* Kb = ws + 2 * SZ;
  ushort_t* Vtb = ws + 4 * SZ;  // [B][H][D][S], written by V-GEMM epilogue
  ushort_t* Wqb = ws + 5 * SZ;
  ushort_t* Wkb = Wqb + WSZ;
  ushort_t* Wvb = Wkb + WSZ;
  ushort_t* Wob = Wvb + WSZ;
  ushort_t* Ob = xb;

  f32_to_bf16<<<2048, 256, 0, stream>>>(x, xb, SZ / 4);
  f32_to_bf16<<<1024, 256, 0, stream>>>(Wq, Wqb, WSZ / 4);
  f32_to_bf16<<<1024, 256, 0, stream>>>(Wk, Wkb, WSZ / 4);
  f32_to_bf16<<<1024, 256, 0, stream>>>(Wv, Wvb, WSZ / 4);
  f32_to_bf16<<<1024, 256, 0, stream>>>(Wo, Wob, WSZ / 4);

  gemm256<2><<<256, 512, 0, stream>>>(xb, Wqb, bq, Qb);          // Q proj + RoPE
  gemm256<2><<<256, 512, 0, stream>>>(xb, Wkb, bk, Kb);          // K proj + RoPE
  gemm256<3><<<256, 512, 0, stream>>>(xb, Wvb, bv, Vtb);         // V proj + transpose

  attn_fwd<<<512, 256, 0, stream>>>(Qb, Kb, Vtb, Ob);

  gemm256<1><<<256, 512, 0, stream>>>(Ob, Wob, bo, (void*)out);  // out proj, f32
}

// Round 7
// 447.567 us; speedup vs baseline: 1.1088x; 1.1088x over previous
//
#include <hip/hip_runtime.h>
#include <hip/hip_bf16.h>
#include <stdint.h>

#define B_ 4
#define S_ 2048
#define E_ 2048
#define H_ 16
#define D_ 128
#define M_ (B_ * S_)  // 8192 rows

typedef unsigned short ushort_t;
typedef unsigned int uint_t;
typedef __attribute__((ext_vector_type(4))) float f32x4;
typedef __attribute__((ext_vector_type(2))) uint_t u32x2;
typedef __attribute__((ext_vector_type(8))) short bf16x8;

__device__ __forceinline__ ushort_t f2bf(float f) {
  uint_t u = __float_as_uint(f);
  u += 0x7FFFu + ((u >> 16) & 1u);  // RNE
  return (ushort_t)(u >> 16);
}
__device__ __forceinline__ float bf2f(ushort_t h) {
  return __uint_as_float(((uint_t)h) << 16);
}
__device__ __forceinline__ uint_t cvt_pk_bf16(float lo, float hi) {
  uint_t r;
  asm("v_cvt_pk_bf16_f32 %0, %1, %2" : "=v"(r) : "v"(lo), "v"(hi));
  return r;
}

#define GLOAD_LDS16(gp, lp)                                   \
  __builtin_amdgcn_global_load_lds(                           \
      (__attribute__((address_space(1))) void*)(gp),          \
      (__attribute__((address_space(3))) void*)(lp), 16, 0, 0)

// ---------------------------------------------------------------- converts
__global__ void f32_to_bf16(const float* __restrict__ in, ushort_t* __restrict__ out,
                            size_t n4) {
  const size_t stride = (size_t)gridDim.x * blockDim.x;
  for (size_t i = (size_t)blockIdx.x * blockDim.x + threadIdx.x; i < n4; i += stride) {
    const f32x4 f = __builtin_nontemporal_load((const f32x4*)in + i);
    u32x2 o;
    o[0] = (uint_t)f2bf(f[0]) | ((uint_t)f2bf(f[1]) << 16);
    o[1] = (uint_t)f2bf(f[2]) | ((uint_t)f2bf(f[3]) << 16);
    __builtin_nontemporal_store(o, (u32x2*)out + i);
  }
}

// ---------------------------------------------------------------- RoPE cos/sin table
// tab[s*64+p] = (cos, sin) of s * 10000^(-2p/128).  2048*64 entries = 1 MB.
__global__ void rope_table(float2* __restrict__ tab) {
  const int i = blockIdx.x * 256 + threadIdx.x;  // grid 512 -> 131072
  const int s = i >> 6, p = i & 63;
  const float inv = exp2f(-0.20762050593046f * (float)p);  // log2(10000)/64
  float sn, cs;
  sincosf((float)s * inv, &sn, &cs);
  tab[i] = make_float2(cs, sn);
}

// ---------------------------------------------------------------- V transpose: [M][E] -> [B][H][D][S]
__global__ __launch_bounds__(256) void transpose_v(const ushort_t* __restrict__ Vp,
                                                   ushort_t* __restrict__ Vt) {
  const int b = blockIdx.z, h = blockIdx.y;
  const int s0 = blockIdx.x * 64;
  const int tid = threadIdx.x;
  __shared__ ushort_t T[64][136];
#pragma unroll
  for (int i = 0; i < 4; i++) {
    const int c = i * 256 + tid;
    const int s = c >> 4, d8 = c & 15;
    *(bf16x8*)(&T[s][d8 * 8]) =
        *(const bf16x8*)(Vp + (size_t)(b * S_ + s0 + s) * E_ + h * D_ + d8 * 8);
  }
  __syncthreads();
#pragma unroll
  for (int i = 0; i < 4; i++) {
    const int c = i * 256 + tid;
    const int d = c >> 3, s8 = c & 7;
    bf16x8 v;
#pragma unroll
    for (int j = 0; j < 8; j++) v[j] = (short)T[s8 * 8 + j][d];
    *(bf16x8*)(Vt + ((size_t)(b * H_ + h) * D_ + d) * S_ + s0 + s8 * 8) = v;
  }
}

// ---------------------------------------------------------------- GEMM 128x128 (proven m97-style)
// C[M][N] = A[M][K]·Bw[N][K]^T + bias. MODE 0: bf16. MODE 1: f32. MODE 2: bf16+RoPE(table).
template <int MODE>
__global__ __launch_bounds__(256, 2) void gemm_bt(const ushort_t* __restrict__ A,
                                                  const ushort_t* __restrict__ Bw,
                                                  const float* __restrict__ bias,
                                                  const float2* __restrict__ tab,
                                                  void* __restrict__ Cv) {
  __shared__ ushort_t As[128 * 64];
  __shared__ ushort_t Bs[128 * 64];
  const int tid = threadIdx.x;
  const int w = tid >> 6, l = tid & 63, g = l >> 4, ln = l & 15;
  const int wm = w >> 1, wn = w & 1;
  const int flat = blockIdx.y * 16 + blockIdx.x;
  const int swz = (flat & 7) * 128 + (flat >> 3);
  const int m0 = (swz >> 4) * 128, n0 = (swz & 15) * 128;

  f32x4 acc[4][4];
#pragma unroll
  for (int i = 0; i < 4; i++)
#pragma unroll
    for (int j = 0; j < 4; j++)
#pragma unroll
      for (int r = 0; r < 4; r++) acc[i][j][r] = 0.f;

  const ushort_t* Ab = A + (size_t)m0 * E_;
  const ushort_t* Bb = Bw + (size_t)n0 * E_;

  for (int k0 = 0; k0 < E_; k0 += 64) {
    __syncthreads();
#pragma unroll
    for (int i = 0; i < 4; i++) {
      const int c = i * 256 + tid;
      const int row = c >> 3;
      const int gs = (c & 7) ^ (row & 7);
      GLOAD_LDS16(Ab + (size_t)row * E_ + k0 + gs * 8, (char*)As + (i * 256 + w * 64) * 16);
      GLOAD_LDS16(Bb + (size_t)row * E_ + k0 + gs * 8, (char*)Bs + (i * 256 + w * 64) * 16);
    }
    __syncthreads();
#pragma unroll
    for (int kk = 0; kk < 2; kk++) {
      bf16x8 af[4], bfr[4];
#pragma unroll
      for (int mi = 0; mi < 4; mi++) {
        const int row = wm * 64 + mi * 16 + ln;
        const int sl = (kk * 4 + g) ^ (row & 7);
        af[mi] = *(const bf16x8*)(As + row * 64 + sl * 8);
      }
#pragma unroll
      for (int ni = 0; ni < 4; ni++) {
        const int row = wn * 64 + ni * 16 + ln;
        const int sl = (kk * 4 + g) ^ (row & 7);
        bfr[ni] = *(const bf16x8*)(Bs + row * 64 + sl * 8);
      }
#pragma unroll
      for (int mi = 0; mi < 4; mi++)
#pragma unroll
        for (int ni = 0; ni < 4; ni++)
          acc[mi][ni] =
              __builtin_amdgcn_mfma_f32_16x16x32_bf16(af[mi], bfr[ni], acc[mi][ni], 0, 0, 0);
    }
  }

  float bv[4];
#pragma unroll
  for (int ni = 0; ni < 4; ni++) bv[ni] = bias[n0 + wn * 64 + ni * 16 + ln];
#pragma unroll
  for (int mi = 0; mi < 4; mi++)
#pragma unroll
    for (int ni = 0; ni < 4; ni++) {
      const int col = n0 + wn * 64 + ni * 16 + ln;
      const int p = (col & 127) >> 1;          // RoPE pair index (MODE 2)
      const float sgn = (col & 1) ? 1.f : -1.f;
#pragma unroll
      for (int r = 0; r < 4; r++) {
        const float v = acc[mi][ni][r] + bv[ni];
        const size_t row = m0 + wm * 64 + mi * 16 + g * 4 + r;
        if (MODE == 1) {
          ((float*)Cv)[row * E_ + col] = v;
        } else if (MODE == 2) {
          const float partner = __shfl_xor(v, 1);
          const float2 t = tab[(row & (S_ - 1)) * 64 + p];
          ((ushort_t*)Cv)[row * E_ + col] = f2bf(v * t.x + sgn * partner * t.y);
        } else {
          ((ushort_t*)Cv)[row * E_ + col] = f2bf(v);
        }
      }
    }
}

// ---------------------------------------------------------------- GEMM 256x256, BK=64 (EXPERIMENT)
// Single instantiation, no transcendentals, explicit 2-waves/EU VGPR budget.
// 4 phases/K-tile: {ds_read subtile || stage 1 slab -> barrier -> lgkmcnt(0) ->
// 16 MFMA (setprio)}, counted vmcnt(4), never drained mid-loop. RoPE via table.
__global__ __launch_bounds__(512, 2) void gemm_k256(const ushort_t* __restrict__ A,
                                                    const ushort_t* __restrict__ Bw,
                                                    const float* __restrict__ bias,
                                                    const float2* __restrict__ tab,
                                                    ushort_t* __restrict__ Cv) {
  __shared__ __align__(16) char lds[131072];  // 2 bufs x (A 32KB + B 32KB)
  const int tid = threadIdx.x;
  const int w = tid >> 6, l = tid & 63, g = l >> 4, ln = l & 15;
  const int wm = w >> 2, wn = w & 3;

  const int flat = blockIdx.x;  // 256 blocks; XCD-chunked bijective swizzle
  const int swz = (flat & 7) * 32 + (flat >> 3);
  const int m0 = (swz >> 3) * 256, n0 = (swz & 7) * 256;

  const ushort_t* Ab = A + (size_t)m0 * E_;
  const ushort_t* Bb = Bw + (size_t)n0 * E_;

  int srcRow[2], srcCc[2];
#pragma unroll
  for (int i = 0; i < 2; i++) {
    const int c = i * 512 + tid;       // chunk 0..1023 of one 16KB slab
    const int r2 = c >> 3;             // row-pair 0..127
    const int j = (c & 7) ^ (r2 & 7);  // inverse chunk-XOR swizzle
    srcRow[i] = 2 * r2 + (j >> 2);
    srcCc[i] = (j & 3) * 8;
  }

  const int NT = E_ / 64;  // 32 K-tiles

  auto STAGE = [&](int t_, int mat, int kk) {
    char* dst = lds + (t_ & 1) * 65536 + mat * 32768 + kk * 16384;
    const ushort_t* src = mat ? Bb : Ab;
#pragma unroll
    for (int i = 0; i < 2; i++)
      GLOAD_LDS16(src + (size_t)srcRow[i] * E_ + t_ * 64 + kk * 32 + srcCc[i],
                  dst + (i * 512 + w * 64) * 16);
  };

  const int rp = ln >> 1;
  const int chunkl = ((((ln & 1) << 2) | g) ^ rp);
  const int aBase = wm * 8192 + rp * 128 + chunkl * 16;          // + kk*16384 + mh*4096 + ai*1024
  const int bBase = 32768 + wn * 4096 + rp * 128 + chunkl * 16;  // + kk*16384 + ni*1024

  f32x4 acc[8][4];
#pragma unroll
  for (int mi = 0; mi < 8; mi++)
#pragma unroll
    for (int ni = 0; ni < 4; ni++)
#pragma unroll
      for (int r = 0; r < 4; r++) acc[mi][ni][r] = 0.f;

  STAGE(0, 0, 0);
  STAGE(0, 1, 0);
  STAGE(0, 0, 1);
  STAGE(0, 1, 1);

  for (int t = 0; t < NT; t++) {
    const char* bp = lds + (t & 1) * 65536;
    const bool nxt = (t + 1 < NT);
    bf16x8 bfr[4], af[4];

    // ---- phase 0 (kk=0, mh=0)
    if (nxt)
      asm volatile("s_waitcnt vmcnt(4)" ::: "memory");
    else
      asm volatile("s_waitcnt vmcnt(0)" ::: "memory");
    __builtin_amdgcn_s_barrier();
#pragma unroll
    for (int ni = 0; ni < 4; ni++) bfr[ni] = *(const bf16x8*)(bp + bBase + ni * 1024);
#pragma unroll
    for (int ai = 0; ai < 4; ai++) af[ai] = *(const bf16x8*)(bp + aBase + ai * 1024);
    if (nxt) STAGE(t + 1, 0, 0);
    asm volatile("s_waitcnt lgkmcnt(0)" ::: "memory");
    __builtin_amdgcn_sched_barrier(0);
    __builtin_amdgcn_s_setprio(1);
#pragma unroll
    for (int ai = 0; ai < 4; ai++)
#pragma unroll
      for (int ni = 0; ni < 4; ni++)
        acc[ai][ni] = __builtin_amdgcn_mfma_f32_16x16x32_bf16(af[ai], bfr[ni], acc[ai][ni], 0, 0, 0);
    __builtin_amdgcn_s_setprio(0);

    // ---- phase 1 (kk=0, mh=1)
    __builtin_amdgcn_s_barrier();
#pragma unroll
    for (int ai = 0; ai < 4; ai++) af[ai] = *(const bf16x8*)(bp + aBase + 4096 + ai * 1024);
    if (nxt) STAGE(t + 1, 1, 0);
    asm volatile("s_waitcnt lgkmcnt(0)" ::: "memory");
    __builtin_amdgcn_sched_barrier(0);
    __builtin_amdgcn_s_setprio(1);
#pragma unroll
    for (int ai = 0; ai < 4; ai++)
#pragma unroll
      for (int ni = 0; ni < 4; ni++)
        acc[4 + ai][ni] =
            __builtin_amdgcn_mfma_f32_16x16x32_bf16(af[ai], bfr[ni], acc[4 + ai][ni], 0, 0, 0);
    __builtin_amdgcn_s_setprio(0);

    // ---- phase 2 (kk=1, mh=0)
    if (nxt)
      asm volatile("s_waitcnt vmcnt(4)" ::: "memory");
    else
      asm volatile("s_waitcnt vmcnt(0)" ::: "memory");
    __builtin_amdgcn_s_barrier();
#pragma unroll
    for (int ni = 0; ni < 4; ni++) bfr[ni] = *(const bf16x8*)(bp + bBase + 16384 + ni * 1024);
#pragma unroll
    for (int ai = 0; ai < 4; ai++) af[ai] = *(const bf16x8*)(bp + aBase + 16384 + ai * 1024);
    if (nxt) STAGE(t + 1, 0, 1);
    asm volatile("s_waitcnt lgkmcnt(0)" ::: "memory");
    __builtin_amdgcn_sched_barrier(0);
    __builtin_amdgcn_s_setprio(1);
#pragma unroll
    for (int ai = 0; ai < 4; ai++)
#pragma unroll
      for (int ni = 0; ni < 4; ni++)
        acc[ai][ni] = __builtin_amdgcn_mfma_f32_16x16x32_bf16(af[ai], bfr[ni], acc[ai][ni], 0, 0, 0);
    __builtin_amdgcn_s_setprio(0);

    // ---- phase 3 (kk=1, mh=1)
    __builtin_amdgcn_s_barrier();
#pragma unroll
    for (int ai = 0; ai < 4; ai++)
      af[ai] = *(const bf16x8*)(bp + aBase + 16384 + 4096 + ai * 1024);
    if (nxt) STAGE(t + 1, 1, 1);
    asm volatile("s_waitcnt lgkmcnt(0)" ::: "memory");
    __builtin_amdgcn_sched_barrier(0);
    __builtin_amdgcn_s_setprio(1);
#pragma unroll
    for (int ai = 0; ai < 4; ai++)
#pragma unroll
      for (int ni = 0; ni < 4; ni++)
        acc[4 + ai][ni] =
            __builtin_amdgcn_mfma_f32_16x16x32_bf16(af[ai], bfr[ni], acc[4 + ai][ni], 0, 0, 0);
    __builtin_amdgcn_s_setprio(0);
  }

  // ---------------- epilogue: bias + RoPE(table), scalar bf16 stores
  float bv[4];
#pragma unroll
  for (int ni = 0; ni < 4; ni++) bv[ni] = bias[n0 + wn * 64 + ni * 16 + ln];
#pragma unroll
  for (int mi = 0; mi < 8; mi++)
#pragma unroll
    for (int ni = 0; ni < 4; ni++) {
      const int col = n0 + wn * 64 + ni * 16 + ln;
      const int p = (col & 127) >> 1;
      const float sgn = (col & 1) ? 1.f : -1.f;
      const int row0 = m0 + wm * 128 + mi * 16 + g * 4;
#pragma unroll
      for (int r = 0; r < 4; r++) {
        const float v = acc[mi][ni][r] + bv[ni];
        const float partner = __shfl_xor(v, 1);
        const float2 t = tab[((row0 + r) & (S_ - 1)) * 64 + p];
        Cv[(size_t)(row0 + r) * E_ + col] = f2bf(v * t.x + sgn * partner * t.y);
      }
    }
}

// ---------------------------------------------------------------- flash attention (causal)
// (unchanged: balanced pairs, swapped QK^T, counted vmcnt, defer-max, XCD-grouped grid)
__global__ __launch_bounds__(256, 2) void attn_fwd(const ushort_t* __restrict__ Q,
                                                   const ushort_t* __restrict__ K,
                                                   const ushort_t* __restrict__ Vt,
                                                   ushort_t* __restrict__ O) {
  const int flat = blockIdx.x;
  const int pair = flat >> 6;   // 0..7
  const int bh = flat & 63;     // XCD = bh%8 for all 8 pairs of this bh
  const int b = bh >> 4, h = bh & 15;
  const int tid = threadIdx.x;
  const int w = tid >> 6, l = tid & 63, g = l >> 4, ln = l & 15;

  __shared__ ushort_t Ks[2][64 * 128];  // 32 KB
  __shared__ ushort_t Vs[2][128 * 64];  // 32 KB
  __shared__ ushort_t Ps[4][32 * 64];   // 16 KB, XOR-swizzled rows

  const ushort_t* Kb = K + (size_t)(b * S_) * E_ + h * D_;
  const ushort_t* Vb = Vt + (size_t)(b * H_ + h) * D_ * S_;
  const float scale = 0.08838834764831845f;  // D^-0.5

#define STAGE_KV(buf, kv0_)                                                      \
  do {                                                                           \
    _Pragma("unroll") for (int i = 0; i < 4; i++) {                              \
      const int c = i * 256 + tid;                                               \
      const int row = c >> 4, sl = c & 15;                                       \
      const int gs = sl ^ (row & 7);                                             \
      GLOAD_LDS16(Kb + (size_t)((kv0_) + row) * E_ + gs * 8,                     \
                  (char*)(&Ks[buf][0]) + (i * 256 + w * 64) * 16);               \
    }                                                                            \
    _Pragma("unroll") for (int i = 0; i < 4; i++) {                              \
      const int c = i * 256 + tid;                                               \
      const int row = c >> 3, sl = c & 7;                                        \
      const int gs = sl ^ (row & 7);                                             \
      GLOAD_LDS16(Vb + (size_t)row * S_ + (kv0_) + gs * 8,                       \
                  (char*)(&Vs[buf][0]) + (i * 256 + w * 64) * 16);               \
    }                                                                            \
  } while (0)

  for (int pass = 0; pass < 2; pass++) {
    const int u = (pass == 0) ? pair : (15 - pair);
    const int q0 = u * 128;
    const int wrow0 = q0 + w * 32;

    bf16x8 qf[2][4];
    {
      const ushort_t* qb = Q + (size_t)(b * S_ + wrow0) * E_ + h * D_;
#pragma unroll
      for (int mi = 0; mi < 2; mi++)
#pragma unroll
        for (int kk = 0; kk < 4; kk++) {
          bf16x8 v = *(const bf16x8*)(qb + (size_t)(mi * 16 + ln) * E_ + kk * 32 + g * 8);
#pragma unroll
          for (int j = 0; j < 8; j++) v[j] = (short)f2bf(bf2f((ushort_t)v[j]) * scale);
          qf[mi][kk] = v;
        }
    }

    f32x4 oacc[2][8];
#pragma unroll
    for (int mi = 0; mi < 2; mi++)
#pragma unroll
      for (int nd = 0; nd < 8; nd++)
#pragma unroll
        for (int r = 0; r < 4; r++) oacc[mi][nd][r] = 0.f;
    float mrun[2], srun[2];
#pragma unroll
    for (int mi = 0; mi < 2; mi++) {
      mrun[mi] = -__builtin_inff();
      srun[mi] = 0.f;
    }

    const int ntu = 2 * u + 2;
    STAGE_KV(0, 0);

    for (int t = 0; t < ntu; t++) {
      const int kv0 = t * 64;
      const int cur = t & 1;
      if (t + 1 < ntu) {
        STAGE_KV(cur ^ 1, kv0 + 64);
        asm volatile("s_waitcnt vmcnt(8)" ::: "memory");
      } else {
        asm volatile("s_waitcnt vmcnt(0)" ::: "memory");
      }
      __builtin_amdgcn_s_barrier();
      __builtin_amdgcn_sched_barrier(0);

      if (kv0 <= wrow0 + 31) {
        const ushort_t* Kst = &Ks[cur][0];
        const ushort_t* Vst = &Vs[cur][0];
        f32x4 sa[2][4];
#pragma unroll
        for (int mi = 0; mi < 2; mi++)
#pragma unroll
          for (int ni = 0; ni < 4; ni++)
#pragma unroll
            for (int r = 0; r < 4; r++) sa[mi][ni][r] = 0.f;
        __builtin_amdgcn_s_setprio(1);
#pragma unroll
        for (int kk = 0; kk < 4; kk++) {
          bf16x8 kf[4];
#pragma unroll
          for (int ni = 0; ni < 4; ni++) {
            const int row = ni * 16 + ln;
            const int sl = (kk * 4 + g) ^ (row & 7);
            kf[ni] = *(const bf16x8*)(Kst + row * 128 + sl * 8);
          }
#pragma unroll
          for (int mi = 0; mi < 2; mi++)
#pragma unroll
            for (int ni = 0; ni < 4; ni++)
              sa[mi][ni] =
                  __builtin_amdgcn_mfma_f32_16x16x32_bf16(kf[ni], qf[mi][kk], sa[mi][ni], 0, 0, 0);
        }
        __builtin_amdgcn_s_setprio(0);
        if (kv0 + 63 > wrow0) {
#pragma unroll
          for (int mi = 0; mi < 2; mi++) {
            const int lim = wrow0 + mi * 16 + ln - kv0;
#pragma unroll
            for (int ni = 0; ni < 4; ni++)
#pragma unroll
              for (int r = 0; r < 4; r++)
                if (ni * 16 + g * 4 + r > lim) sa[mi][ni][r] = -__builtin_inff();
          }
        }
#pragma unroll
        for (int mi = 0; mi < 2; mi++) {
          float vmax = -__builtin_inff();
#pragma unroll
          for (int ni = 0; ni < 4; ni++)
#pragma unroll
            for (int r = 0; r < 4; r++) vmax = fmaxf(vmax, sa[mi][ni][r]);
          vmax = fmaxf(vmax, __shfl_xor(vmax, 16));
          vmax = fmaxf(vmax, __shfl_xor(vmax, 32));
          if (!__all(vmax - mrun[mi] <= 8.0f)) {  // T13 defer-max
            const float mnew = fmaxf(mrun[mi], vmax);
            const float fs = __expf(mrun[mi] - mnew);
            mrun[mi] = mnew;
            srun[mi] *= fs;
#pragma unroll
            for (int nd = 0; nd < 8; nd++)
#pragma unroll
              for (int r = 0; r < 4; r++) oacc[mi][nd][r] *= fs;
          }
          const float m = mrun[mi];
          float psum = 0.f;
#pragma unroll
          for (int ni = 0; ni < 4; ni++) {
            float p0 = __expf(sa[mi][ni][0] - m);
            float p1 = __expf(sa[mi][ni][1] - m);
            float p2 = __expf(sa[mi][ni][2] - m);
            float p3 = __expf(sa[mi][ni][3] - m);
            psum += (p0 + p1) + (p2 + p3);
            const int byteW =
                (((mi * 16 + ln) * 64 + ni * 16 + g * 4) * 2) ^ ((ln & 7) << 4);
            *(uint2*)((char*)(&Ps[w][0]) + byteW) =
                make_uint2(cvt_pk_bf16(p0, p1), cvt_pk_bf16(p2, p3));
          }
          psum += __shfl_xor(psum, 16);
          psum += __shfl_xor(psum, 32);
          srun[mi] += psum;
        }
        asm volatile("s_waitcnt lgkmcnt(0)" ::: "memory");
        __builtin_amdgcn_sched_barrier(0);
        __builtin_amdgcn_s_setprio(1);
#pragma unroll
        for (int ks = 0; ks < 2; ks++) {
          bf16x8 pf[2];
#pragma unroll
          for (int mi = 0; mi < 2; mi++) {
            const int byteR =
                (((mi * 16 + ln) * 64 + ks * 32 + g * 8) * 2) ^ ((ln & 7) << 4);
            pf[mi] = *(const bf16x8*)((const char*)(&Ps[w][0]) + byteR);
          }
#pragma unroll
          for (int nd = 0; nd < 8; nd++) {
            const int row = nd * 16 + ln;
            const int sl = (ks * 4 + g) ^ (row & 7);
            const bf16x8 vf = *(const bf16x8*)(Vst + row * 64 + sl * 8);
#pragma unroll
            for (int mi = 0; mi < 2; mi++)
              oacc[mi][nd] =
                  __builtin_amdgcn_mfma_f32_16x16x32_bf16(vf, pf[mi], oacc[mi][nd], 0, 0, 0);
          }
        }
        __builtin_amdgcn_s_setprio(0);
      }
      __builtin_amdgcn_s_barrier();
    }

    // ---- epilogue
    {
      ushort_t* Ob = O + (size_t)(b * S_ + q0 + w * 32) * E_ + h * D_;
#pragma unroll
      for (int mi = 0; mi < 2; mi++) {
        const float inv = 1.0f / srun[mi];
#pragma unroll
        for (int nd = 0; nd < 8; nd++) {
          const uint_t lo = cvt_pk_bf16(oacc[mi][nd][0] * inv, oacc[mi][nd][1] * inv);
          const uint_t hi = cvt_pk_bf16(oacc[mi][nd][2] * inv, oacc[mi][nd][3] * inv);
          *(uint2*)(Ob + (size_t)(mi * 16 + ln) * E_ + nd * 16 + g * 4) = make_uint2(lo, hi);
        }
      }
    }
  }
#undef STAGE_KV
}

// ---------------------------------------------------------------- launch
extern "C" void kernel_launch(void* const* d_in, const int* in_sizes, int n_in,
                              void* d_out, int out_size, void* d_ws, size_t ws_size,
                              hipStream_t stream) {
  const float* x = (const float*)d_in[0];
  const float* Wq = (const float*)d_in[1];
  const float* bq = (const float*)d_in[2];
  const float* Wk = (const float*)d_in[3];
  const float* bk = (const float*)d_in[4];
  const float* Wv = (const float*)d_in[5];
  const float* bv = (const float*)d_in[6];
  const float* Wo = (const float*)d_in[7];
  const float* bo = (const float*)d_in[8];
  float* out = (float*)d_out;

  ushort_t* ws = (ushort_t*)d_ws;
  const size_t SZ = (size_t)M_ * E_;   // 16,777,216
  const size_t WSZ = (size_t)E_ * E_;  // 4,194,304
  ushort_t* xb = ws;             // x bf16; reused as attention output
  ushort_t* Qb = ws + SZ;
  ushort_t* Kb = ws + 2 * SZ;
  float2* tbl = (float2*)(ws + 3 * SZ);  // 1 MB; later overwritten by Vb
  ushort_t* Vb = ws + 3 * SZ;
  ushort_t* Vtb = ws + 4 * SZ;
  ushort_t* Wqb = ws + 5 * SZ;
  ushort_t* Wkb = Wqb + WSZ;
  ushort_t* Wvb = Wkb + WSZ;
  ushort_t* Wob = Wvb + WSZ;
  ushort_t* Ob = xb;

  f32_to_bf16<<<2048, 256, 0, stream>>>(x, xb, SZ / 4);
  f32_to_bf16<<<1024, 256, 0, stream>>>(Wq, Wqb, WSZ / 4);
  f32_to_bf16<<<1024, 256, 0, stream>>>(Wk, Wkb, WSZ / 4);
  f32_to_bf16<<<1024, 256, 0, stream>>>(Wv, Wvb, WSZ / 4);
  f32_to_bf16<<<1024, 256, 0, stream>>>(Wo, Wob, WSZ / 4);
  rope_table<<<512, 256, 0, stream>>>(tbl);

  dim3 gg(16, 64);
  gemm_bt<2><<<gg, 256, 0, stream>>>(xb, Wqb, bq, tbl, Qb);       // Q: 128^2 + RoPE
  gemm_k256<<<256, 512, 0, stream>>>(xb, Wkb, bk, tbl, Kb);       // K: 256^2 experiment + RoPE
  gemm_bt<0><<<gg, 256, 0, stream>>>(xb, Wvb, bv, nullptr, Vb);   // V: plain bf16
  transpose_v<<<dim3(32, H_, B_), 256, 0, stream>>>(Vb, Vtb);

  attn_fwd<<<512, 256, 0, stream>>>(Qb, Kb, Vtb, Ob);

  gemm_bt<1><<<gg, 256, 0, stream>>>(Ob, Wob, bo, nullptr, (void*)out);  // O: f32
}

// Round 8
// 424.169 us; speedup vs baseline: 1.1700x; 1.0552x over previous
//
#include <hip/hip_runtime.h>
#include <hip/hip_bf16.h>
#include <stdint.h>

#define B_ 4
#define S_ 2048
#define E_ 2048
#define H_ 16
#define D_ 128
#define M_ (B_ * S_)  // 8192 rows

typedef unsigned short ushort_t;
typedef unsigned int uint_t;
typedef __attribute__((ext_vector_type(4))) float f32x4;
typedef __attribute__((ext_vector_type(2))) uint_t u32x2;
typedef __attribute__((ext_vector_type(8))) short bf16x8;

__device__ __forceinline__ ushort_t f2bf(float f) {
  uint_t u = __float_as_uint(f);
  u += 0x7FFFu + ((u >> 16) & 1u);  // RNE
  return (ushort_t)(u >> 16);
}
__device__ __forceinline__ float bf2f(ushort_t h) {
  return __uint_as_float(((uint_t)h) << 16);
}
__device__ __forceinline__ uint_t cvt_pk_bf16(float lo, float hi) {
  uint_t r;
  asm("v_cvt_pk_bf16_f32 %0, %1, %2" : "=v"(r) : "v"(lo), "v"(hi));
  return r;
}

#define GLOAD_LDS16(gp, lp)                                   \
  __builtin_amdgcn_global_load_lds(                           \
      (__attribute__((address_space(1))) void*)(gp),          \
      (__attribute__((address_space(3))) void*)(lp), 16, 0, 0)

// ---------------------------------------------------------------- converts
__global__ void f32_to_bf16(const float* __restrict__ in, ushort_t* __restrict__ out,
                            size_t n4) {
  const size_t stride = (size_t)gridDim.x * blockDim.x;
  for (size_t i = (size_t)blockIdx.x * blockDim.x + threadIdx.x; i < n4; i += stride) {
    const f32x4 f = __builtin_nontemporal_load((const f32x4*)in + i);
    u32x2 o;
    o[0] = (uint_t)f2bf(f[0]) | ((uint_t)f2bf(f[1]) << 16);
    o[1] = (uint_t)f2bf(f[2]) | ((uint_t)f2bf(f[3]) << 16);
    __builtin_nontemporal_store(o, (u32x2*)out + i);
  }
}

// ---------------------------------------------------------------- RoPE cos/sin table
__global__ void rope_table(float2* __restrict__ tab) {
  const int i = blockIdx.x * 256 + threadIdx.x;  // grid 512 -> 131072
  const int s = i >> 6, p = i & 63;
  const float inv = exp2f(-0.20762050593046f * (float)p);  // 10000^(-2p/128)
  float sn, cs;
  sincosf((float)s * inv, &sn, &cs);
  tab[i] = make_float2(cs, sn);
}

// ---------------------------------------------------------------- V transpose: [M][E] -> [B][H][D][S]
__global__ __launch_bounds__(256) void transpose_v(const ushort_t* __restrict__ Vp,
                                                   ushort_t* __restrict__ Vt) {
  const int b = blockIdx.z, h = blockIdx.y;
  const int s0 = blockIdx.x * 64;
  const int tid = threadIdx.x;
  __shared__ ushort_t T[64][136];
#pragma unroll
  for (int i = 0; i < 4; i++) {
    const int c = i * 256 + tid;
    const int s = c >> 4, d8 = c & 15;
    *(bf16x8*)(&T[s][d8 * 8]) =
        *(const bf16x8*)(Vp + (size_t)(b * S_ + s0 + s) * E_ + h * D_ + d8 * 8);
  }
  __syncthreads();
#pragma unroll
  for (int i = 0; i < 4; i++) {
    const int c = i * 256 + tid;
    const int d = c >> 3, s8 = c & 7;
    bf16x8 v;
#pragma unroll
    for (int j = 0; j < 8; j++) v[j] = (short)T[s8 * 8 + j][d];
    *(bf16x8*)(Vt + ((size_t)(b * H_ + h) * D_ + d) * S_ + s0 + s8 * 8) = v;
  }
}

// ---------------------------------------------------------------- GEMM 256x256, BK=64, 8 waves,
// faithful m201 8-phase schedule. Phase = (kk, m-half): {4-8 ds_read_b128 || stage 1 slab
// (2 gload_lds) -> s_barrier -> lgkmcnt(0)+sched_barrier -> 16 MFMA (setprio)} x 8 per
// 2 K-tiles. Slabs = (matrix, kk) 16KB. vmcnt(6) ONLY at phases 4/8 (3 slabs in flight,
// prefetch distance 2 K-tiles); B-frags register-held across the 2 m-half phases.
// All barriers/waits are asm volatile ::: "memory" (no compiler drain, no hoist races).
// MODE 0: bf16. MODE 1: f32. MODE 2: bf16 + RoPE(table).
template <int MODE>
__global__ __launch_bounds__(512, 2) void gemm8p(const ushort_t* __restrict__ A,
                                                 const ushort_t* __restrict__ Bw,
                                                 const float* __restrict__ bias,
                                                 const float2* __restrict__ tab,
                                                 void* __restrict__ Cv) {
  // buf0 [0,64K): T_even; buf1 [64K,128K): T_odd. Within buf: A-k0, A-k1, B-k0, B-k1 (16KB each).
  __shared__ __align__(16) char lds[131072];
  const int tid = threadIdx.x;
  const int w = tid >> 6, l = tid & 63, g = l >> 4, ln = l & 15;
  const int wm = w >> 2, wn = w & 3;

  const int flat = blockIdx.x;  // 256 blocks; XCD-chunked bijective swizzle
  const int swz = (flat & 7) * 32 + (flat >> 3);
  const int m0 = (swz >> 3) * 256, n0 = (swz & 7) * 256;

  const ushort_t* Ab = A + (size_t)m0 * E_;
  const ushort_t* Bb = Bw + (size_t)n0 * E_;

  int srcRow[2], srcCc[2];
#pragma unroll
  for (int i = 0; i < 2; i++) {
    const int c = i * 512 + tid;       // chunk 0..1023 of one 16KB slab
    const int r2 = c >> 3;             // row-pair 0..127
    const int j = (c & 7) ^ (r2 & 7);  // inverse chunk-XOR swizzle
    srcRow[i] = 2 * r2 + (j >> 2);
    srcCc[i] = (j & 3) * 8;
  }

  auto STAGE = [&](int t_, int mat, int kk) {
    char* dst = lds + (t_ & 1) * 65536 + mat * 32768 + kk * 16384;
    const ushort_t* src = mat ? Bb : Ab;
#pragma unroll
    for (int i = 0; i < 2; i++)
      GLOAD_LDS16(src + (size_t)srcRow[i] * E_ + t_ * 64 + kk * 32 + srcCc[i],
                  dst + (i * 512 + w * 64) * 16);
  };

  const int rp = ln >> 1;
  const int chunkl = ((((ln & 1) << 2) | g) ^ rp);
  const int aBase = wm * 8192 + rp * 128 + chunkl * 16;          // + kk*16384 + mh*4096 + ai*1024
  const int bBase = 32768 + wn * 4096 + rp * 128 + chunkl * 16;  // + kk*16384 + ni*1024

  f32x4 acc[8][4];
#pragma unroll
  for (int mi = 0; mi < 8; mi++)
#pragma unroll
    for (int ni = 0; ni < 4; ni++)
#pragma unroll
      for (int r = 0; r < 4; r++) acc[mi][ni][r] = 0.f;

#define BARR asm volatile("s_barrier" ::: "memory")
#define VM6 asm volatile("s_waitcnt vmcnt(6)" ::: "memory")
#define VM0 asm volatile("s_waitcnt vmcnt(0)" ::: "memory")
#define LGKM0                                            \
  do {                                                   \
    asm volatile("s_waitcnt lgkmcnt(0)" ::: "memory");   \
    __builtin_amdgcn_sched_barrier(0);                   \
  } while (0)
#define PH_RDB(bp, kk)                                                         \
  _Pragma("unroll") for (int ni = 0; ni < 4; ni++) bfr[ni] =                   \
      *(const bf16x8*)((bp) + bBase + (kk)*16384 + ni * 1024);
#define PH_RDA(bp, kk, mh)                                                     \
  _Pragma("unroll") for (int ai = 0; ai < 4; ai++) af[ai] =                    \
      *(const bf16x8*)((bp) + aBase + (kk)*16384 + (mh)*4096 + ai * 1024);
#define PH_MM(mh)                                                              \
  __builtin_amdgcn_s_setprio(1);                                               \
  _Pragma("unroll") for (int ai = 0; ai < 4; ai++)                             \
      _Pragma("unroll") for (int ni = 0; ni < 4; ni++) acc[(mh)*4 + ai][ni] =  \
          __builtin_amdgcn_mfma_f32_16x16x32_bf16(af[ai], bfr[ni],             \
                                                  acc[(mh)*4 + ai][ni], 0, 0, 0); \
  __builtin_amdgcn_s_setprio(0);

  // prologue: T0 all 4 slabs, T1 {Bk0, Ak0, Bk1}; T1's Ak1 comes in ph1 of iter 0
  STAGE(0, 1, 0); STAGE(0, 0, 0); STAGE(0, 1, 1); STAGE(0, 0, 1);
  STAGE(1, 1, 0); STAGE(1, 0, 0); STAGE(1, 1, 1);
  VM6;  // T0's 4 slabs landed; T1's 3 may fly
  BARR;

  const char* b0 = lds;
  const char* b1 = lds + 65536;
  bf16x8 af[4], bfr[4];

  for (int it = 0; it < 15; ++it) {  // steady state: 2 K-tiles per iteration
    const int t2 = 2 * it;
    PH_RDB(b0, 0); PH_RDA(b0, 0, 0); STAGE(t2 + 1, 0, 1); BARR; LGKM0; PH_MM(0); BARR;
    PH_RDA(b0, 0, 1);                STAGE(t2 + 2, 1, 0); BARR; LGKM0; PH_MM(1); BARR;
    PH_RDB(b0, 1); PH_RDA(b0, 1, 0); STAGE(t2 + 2, 0, 0); BARR; LGKM0; PH_MM(0); BARR;
    PH_RDA(b0, 1, 1);                STAGE(t2 + 2, 1, 1); BARR; LGKM0; PH_MM(1); VM6; BARR;
    PH_RDB(b1, 0); PH_RDA(b1, 0, 0); STAGE(t2 + 2, 0, 1); BARR; LGKM0; PH_MM(0); BARR;
    PH_RDA(b1, 0, 1);                STAGE(t2 + 3, 1, 0); BARR; LGKM0; PH_MM(1); BARR;
    PH_RDB(b1, 1); PH_RDA(b1, 1, 0); STAGE(t2 + 3, 0, 0); BARR; LGKM0; PH_MM(0); BARR;
    PH_RDA(b1, 1, 1);                STAGE(t2 + 3, 1, 1); BARR; LGKM0; PH_MM(1); VM6; BARR;
  }
  // tail: T30 (b0), T31 (b1); only T31's Ak1 still needs staging
  PH_RDB(b0, 0); PH_RDA(b0, 0, 0); STAGE(31, 0, 1); BARR; LGKM0; PH_MM(0); BARR;
  PH_RDA(b0, 0, 1);                                 BARR; LGKM0; PH_MM(1); BARR;
  PH_RDB(b0, 1); PH_RDA(b0, 1, 0);                  BARR; LGKM0; PH_MM(0); BARR;
  PH_RDA(b0, 1, 1);                                 BARR; LGKM0; PH_MM(1); VM0; BARR;
  PH_RDB(b1, 0); PH_RDA(b1, 0, 0);                  BARR; LGKM0; PH_MM(0); BARR;
  PH_RDA(b1, 0, 1);                                 BARR; LGKM0; PH_MM(1); BARR;
  PH_RDB(b1, 1); PH_RDA(b1, 1, 0);                  BARR; LGKM0; PH_MM(0); BARR;
  PH_RDA(b1, 1, 1);                                 BARR; LGKM0; PH_MM(1);

#undef PH_MM
#undef PH_RDA
#undef PH_RDB
#undef LGKM0
#undef VM0
#undef VM6
#undef BARR

  // ---------------- epilogue (proven round-7 scalar form)
  float bv[4];
#pragma unroll
  for (int ni = 0; ni < 4; ni++) bv[ni] = bias[n0 + wn * 64 + ni * 16 + ln];
#pragma unroll
  for (int mi = 0; mi < 8; mi++)
#pragma unroll
    for (int ni = 0; ni < 4; ni++) {
      const int col = n0 + wn * 64 + ni * 16 + ln;
      const int p = (col & 127) >> 1;
      const float sgn = (col & 1) ? 1.f : -1.f;
      const int row0 = m0 + wm * 128 + mi * 16 + g * 4;
#pragma unroll
      for (int r = 0; r < 4; r++) {
        const float v = acc[mi][ni][r] + bv[ni];
        if (MODE == 1) {
          ((float*)Cv)[(size_t)(row0 + r) * E_ + col] = v;
        } else if (MODE == 2) {
          const float partner = __shfl_xor(v, 1);
          const float2 t = tab[((row0 + r) & (S_ - 1)) * 64 + p];
          ((ushort_t*)Cv)[(size_t)(row0 + r) * E_ + col] =
              f2bf(v * t.x + sgn * partner * t.y);
        } else {
          ((ushort_t*)Cv)[(size_t)(row0 + r) * E_ + col] = f2bf(v);
        }
      }
    }
}

// ---------------------------------------------------------------- flash attention (causal)
// (FROZEN from round 7: balanced pairs, swapped QK^T, counted vmcnt, defer-max, XCD-grouped)
__global__ __launch_bounds__(256, 2) void attn_fwd(const ushort_t* __restrict__ Q,
                                                   const ushort_t* __restrict__ K,
                                                   const ushort_t* __restrict__ Vt,
                                                   ushort_t* __restrict__ O) {
  const int flat = blockIdx.x;
  const int pair = flat >> 6;   // 0..7
  const int bh = flat & 63;     // XCD = bh%8 for all 8 pairs of this bh
  const int b = bh >> 4, h = bh & 15;
  const int tid = threadIdx.x;
  const int w = tid >> 6, l = tid & 63, g = l >> 4, ln = l & 15;

  __shared__ ushort_t Ks[2][64 * 128];  // 32 KB
  __shared__ ushort_t Vs[2][128 * 64];  // 32 KB
  __shared__ ushort_t Ps[4][32 * 64];   // 16 KB, XOR-swizzled rows

  const ushort_t* Kb = K + (size_t)(b * S_) * E_ + h * D_;
  const ushort_t* Vb = Vt + (size_t)(b * H_ + h) * D_ * S_;
  const float scale = 0.08838834764831845f;  // D^-0.5

#define STAGE_KV(buf, kv0_)                                                      \
  do {                                                                           \
    _Pragma("unroll") for (int i = 0; i < 4; i++) {                              \
      const int c = i * 256 + tid;                                               \
      const int row = c >> 4, sl = c & 15;                                       \
      const int gs = sl ^ (row & 7);                                             \
      GLOAD_LDS16(Kb + (size_t)((kv0_) + row) * E_ + gs * 8,                     \
                  (char*)(&Ks[buf][0]) + (i * 256 + w * 64) * 16);               \
    }                                                                            \
    _Pragma("unroll") for (int i = 0; i < 4; i++) {                              \
      const int c = i * 256 + tid;                                               \
      const int row = c >> 3, sl = c & 7;                                        \
      const int gs = sl ^ (row & 7);                                             \
      GLOAD_LDS16(Vb + (size_t)row * S_ + (kv0_) + gs * 8,                       \
                  (char*)(&Vs[buf][0]) + (i * 256 + w * 64) * 16);               \
    }                                                                            \
  } while (0)

  for (int pass = 0; pass < 2; pass++) {
    const int u = (pass == 0) ? pair : (15 - pair);
    const int q0 = u * 128;
    const int wrow0 = q0 + w * 32;

    bf16x8 qf[2][4];
    {
      const ushort_t* qb = Q + (size_t)(b * S_ + wrow0) * E_ + h * D_;
#pragma unroll
      for (int mi = 0; mi < 2; mi++)
#pragma unroll
        for (int kk = 0; kk < 4; kk++) {
          bf16x8 v = *(const bf16x8*)(qb + (size_t)(mi * 16 + ln) * E_ + kk * 32 + g * 8);
#pragma unroll
          for (int j = 0; j < 8; j++) v[j] = (short)f2bf(bf2f((ushort_t)v[j]) * scale);
          qf[mi][kk] = v;
        }
    }

    f32x4 oacc[2][8];
#pragma unroll
    for (int mi = 0; mi < 2; mi++)
#pragma unroll
      for (int nd = 0; nd < 8; nd++)
#pragma unroll
        for (int r = 0; r < 4; r++) oacc[mi][nd][r] = 0.f;
    float mrun[2], srun[2];
#pragma unroll
    for (int mi = 0; mi < 2; mi++) {
      mrun[mi] = -__builtin_inff();
      srun[mi] = 0.f;
    }

    const int ntu = 2 * u + 2;
    STAGE_KV(0, 0);

    for (int t = 0; t < ntu; t++) {
      const int kv0 = t * 64;
      const int cur = t & 1;
      if (t + 1 < ntu) {
        STAGE_KV(cur ^ 1, kv0 + 64);
        asm volatile("s_waitcnt vmcnt(8)" ::: "memory");
      } else {
        asm volatile("s_waitcnt vmcnt(0)" ::: "memory");
      }
      __builtin_amdgcn_s_barrier();
      __builtin_amdgcn_sched_barrier(0);

      if (kv0 <= wrow0 + 31) {
        const ushort_t* Kst = &Ks[cur][0];
        const ushort_t* Vst = &Vs[cur][0];
        f32x4 sa[2][4];
#pragma unroll
        for (int mi = 0; mi < 2; mi++)
#pragma unroll
          for (int ni = 0; ni < 4; ni++)
#pragma unroll
            for (int r = 0; r < 4; r++) sa[mi][ni][r] = 0.f;
        __builtin_amdgcn_s_setprio(1);
#pragma unroll
        for (int kk = 0; kk < 4; kk++) {
          bf16x8 kf[4];
#pragma unroll
          for (int ni = 0; ni < 4; ni++) {
            const int row = ni * 16 + ln;
            const int sl = (kk * 4 + g) ^ (row & 7);
            kf[ni] = *(const bf16x8*)(Kst + row * 128 + sl * 8);
          }
#pragma unroll
          for (int mi = 0; mi < 2; mi++)
#pragma unroll
            for (int ni = 0; ni < 4; ni++)
              sa[mi][ni] =
                  __builtin_amdgcn_mfma_f32_16x16x32_bf16(kf[ni], qf[mi][kk], sa[mi][ni], 0, 0, 0);
        }
        __builtin_amdgcn_s_setprio(0);
        if (kv0 + 63 > wrow0) {
#pragma unroll
          for (int mi = 0; mi < 2; mi++) {
            const int lim = wrow0 + mi * 16 + ln - kv0;
#pragma unroll
            for (int ni = 0; ni < 4; ni++)
#pragma unroll
              for (int r = 0; r < 4; r++)
                if (ni * 16 + g * 4 + r > lim) sa[mi][ni][r] = -__builtin_inff();
          }
        }
#pragma unroll
        for (int mi = 0; mi < 2; mi++) {
          float vmax = -__builtin_inff();
#pragma unroll
          for (int ni = 0; ni < 4; ni++)
#pragma unroll
            for (int r = 0; r < 4; r++) vmax = fmaxf(vmax, sa[mi][ni][r]);
          vmax = fmaxf(vmax, __shfl_xor(vmax, 16));
          vmax = fmaxf(vmax, __shfl_xor(vmax, 32));
          if (!__all(vmax - mrun[mi] <= 8.0f)) {  // T13 defer-max
            const float mnew = fmaxf(mrun[mi], vmax);
            const float fs = __expf(mrun[mi] - mnew);
            mrun[mi] = mnew;
            srun[mi] *= fs;
#pragma unroll
            for (int nd = 0; nd < 8; nd++)
#pragma unroll
              for (int r = 0; r < 4; r++) oacc[mi][nd][r] *= fs;
          }
          const float m = mrun[mi];
          float psum = 0.f;
#pragma unroll
          for (int ni = 0; ni < 4; ni++) {
            float p0 = __expf(sa[mi][ni][0] - m);
            float p1 = __expf(sa[mi][ni][1] - m);
            float p2 = __expf(sa[mi][ni][2] - m);
            float p3 = __expf(sa[mi][ni][3] - m);
            psum += (p0 + p1) + (p2 + p3);
            const int byteW =
                (((mi * 16 + ln) * 64 + ni * 16 + g * 4) * 2) ^ ((ln & 7) << 4);
            *(uint2*)((char*)(&Ps[w][0]) + byteW) =
                make_uint2(cvt_pk_bf16(p0, p1), cvt_pk_bf16(p2, p3));
          }
          psum += __shfl_xor(psum, 16);
          psum += __shfl_xor(psum, 32);
          srun[mi] += psum;
        }
        asm volatile("s_waitcnt lgkmcnt(0)" ::: "memory");
        __builtin_amdgcn_sched_barrier(0);
        __builtin_amdgcn_s_setprio(1);
#pragma unroll
        for (int ks = 0; ks < 2; ks++) {
          bf16x8 pf[2];
#pragma unroll
          for (int mi = 0; mi < 2; mi++) {
            const int byteR =
                (((mi * 16 + ln) * 64 + ks * 32 + g * 8) * 2) ^ ((ln & 7) << 4);
            pf[mi] = *(const bf16x8*)((const char*)(&Ps[w][0]) + byteR);
          }
#pragma unroll
          for (int nd = 0; nd < 8; nd++) {
            const int row = nd * 16 + ln;
            const int sl = (ks * 4 + g) ^ (row & 7);
            const bf16x8 vf = *(const bf16x8*)(Vst + row * 64 + sl * 8);
#pragma unroll
            for (int mi = 0; mi < 2; mi++)
              oacc[mi][nd] =
                  __builtin_amdgcn_mfma_f32_16x16x32_bf16(vf, pf[mi], oacc[mi][nd], 0, 0, 0);
          }
        }
        __builtin_amdgcn_s_setprio(0);
      }
      __builtin_amdgcn_s_barrier();
    }

    // ---- epilogue
    {
      ushort_t* Ob = O + (size_t)(b * S_ + q0 + w * 32) * E_ + h * D_;
#pragma unroll
      for (int mi = 0; mi < 2; mi++) {
        const float inv = 1.0f / srun[mi];
#pragma unroll
        for (int nd = 0; nd < 8; nd++) {
          const uint_t lo = cvt_pk_bf16(oacc[mi][nd][0] * inv, oacc[mi][nd][1] * inv);
          const uint_t hi = cvt_pk_bf16(oacc[mi][nd][2] * inv, oacc[mi][nd][3] * inv);
          *(uint2*)(Ob + (size_t)(mi * 16 + ln) * E_ + nd * 16 + g * 4) = make_uint2(lo, hi);
        }
      }
    }
  }
#undef STAGE_KV
}

// ---------------------------------------------------------------- launch
extern "C" void kernel_launch(void* const* d_in, const int* in_sizes, int n_in,
                              void* d_out, int out_size, void* d_ws, size_t ws_size,
                              hipStream_t stream) {
  const float* x = (const float*)d_in[0];
  const float* Wq = (const float*)d_in[1];
  const float* bq = (const float*)d_in[2];
  const float* Wk = (const float*)d_in[3];
  const float* bk = (const float*)d_in[4];
  const float* Wv = (const float*)d_in[5];
  const float* bv = (const float*)d_in[6];
  const float* Wo = (const float*)d_in[7];
  const float* bo = (const float*)d_in[8];
  float* out = (float*)d_out;

  ushort_t* ws = (ushort_t*)d_ws;
  const size_t SZ = (size_t)M_ * E_;   // 16,777,216
  const size_t WSZ = (size_t)E_ * E_;  // 4,194,304
  ushort_t* xb = ws;             // x bf16; reused as attention output
  ushort_t* Qb = ws + SZ;
  ushort_t* Kb = ws + 2 * SZ;
  float2* tbl = (float2*)(ws + 3 * SZ);  // 1 MB; later overwritten by Vb
  ushort_t* Vb = ws + 3 * SZ;
  ushort_t* Vtb = ws + 4 * SZ;
  ushort_t* Wqb = ws + 5 * SZ;
  ushort_t* Wkb = Wqb + WSZ;
  ushort_t* Wvb = Wkb + WSZ;
  ushort_t* Wob = Wvb + WSZ;
  ushort_t* Ob = xb;

  f32_to_bf16<<<2048, 256, 0, stream>>>(x, xb, SZ / 4);
  f32_to_bf16<<<1024, 256, 0, stream>>>(Wq, Wqb, WSZ / 4);
  f32_to_bf16<<<1024, 256, 0, stream>>>(Wk, Wkb, WSZ / 4);
  f32_to_bf16<<<1024, 256, 0, stream>>>(Wv, Wvb, WSZ / 4);
  f32_to_bf16<<<1024, 256, 0, stream>>>(Wo, Wob, WSZ / 4);
  rope_table<<<512, 256, 0, stream>>>(tbl);

  gemm8p<2><<<256, 512, 0, stream>>>(xb, Wqb, bq, tbl, Qb);         // Q + RoPE
  gemm8p<2><<<256, 512, 0, stream>>>(xb, Wkb, bk, tbl, Kb);         // K + RoPE
  gemm8p<0><<<256, 512, 0, stream>>>(xb, Wvb, bv, nullptr, Vb);     // V bf16
  transpose_v<<<dim3(32, H_, B_), 256, 0, stream>>>(Vb, Vtb);

  attn_fwd<<<512, 256, 0, stream>>>(Qb, Kb, Vtb, Ob);

  gemm8p<1><<<256, 512, 0, stream>>>(Ob, Wob, bo, nullptr, (void*)out);  // O f32
}